// Round 1
// baseline (9498.605 us; speedup 1.0000x reference)
//
#include <hip/hip_runtime.h>
#include <hip/hip_bf16.h>
#include <hip/hip_cooperative_groups.h>

namespace cg = cooperative_groups;

typedef __bf16 bf16x8 __attribute__((ext_vector_type(8)));
typedef float f32x4 __attribute__((ext_vector_type(4)));

#define B_ 64
#define T_ 512
#define E_ 256
#define U_ 512

// ---------------- workspace layout (bytes) ----------------
// xs_g   : bf16 [T][B][E]  (rows 512B, 16B-granule XOR-swizzled)   16 MiB @ 0
// wslice : bf16 [2][64][32][768] (per-WG transposed weight slices)  6 MiB @ 16 MiB
// h_g    : bf16 [2 dir][2 buf][64][512] (swizzled rows)            256 KiB
// hfin   : f32  [2][64][512] (plain layout, final h)               256 KiB
// total ~23.6 MiB
static const size_t WS_XS = 0;
static const size_t WS_WS = (size_t)16 << 20;
static const size_t WS_HG = ((size_t)16 << 20) + 6291456;
static const size_t WS_HF = ((size_t)16 << 20) + 6291456 + 262144;

// Embedding gather + bf16 convert + granule swizzle.
// one thread per 16B granule: total T*B*32 = 1,048,576 threads
__global__ void embed_swz_kernel(const int* __restrict__ sent,
                                 const float* __restrict__ emb,
                                 __bf16* __restrict__ xs_g) {
  int id = blockIdx.x * 256 + threadIdx.x;
  int gx = id & 31;          // granule within row (32 x 8 bf16 = 256)
  int b  = (id >> 5) & 63;
  int t  = id >> 11;
  int idx = sent[b * T_ + t];            // sentence is [B][T]
  const float* src = emb + (size_t)idx * E_ + gx * 8;
  bf16x8 v;
#pragma unroll
  for (int j = 0; j < 8; ++j) v[j] = (__bf16)src[j];
  int gs = gx ^ (b & 7);                 // XOR swizzle keyed by row (=batch)
  *(bf16x8*)(xs_g + (size_t)(t * 64 + b) * E_ + gs * 8) = v;
}

// Weight prep: build per-WG transposed slices.
// dest[((d*64+s)*32+c)*768 + k]; col c: 0..7=i,8..15=f,16..23=g,24..31=o (units u0..u0+7)
__global__ void wprep_kernel(const float* __restrict__ Wx_f, const float* __restrict__ Wh_f,
                             const float* __restrict__ Wx_b, const float* __restrict__ Wh_b,
                             __bf16* __restrict__ wslice) {
  int id = blockIdx.x * 256 + threadIdx.x;     // [0, 2*64*32*768)
  int k = id % 768;
  int c = (id / 768) & 31;
  int s = (id / (768 * 32)) & 63;
  int d = id / (768 * 32 * 64);
  int n = (c >> 3) * 512 + s * 8 + (c & 7);    // global column in [0,2048)
  const float* Wx = d ? Wx_b : Wx_f;
  const float* Wh = d ? Wh_b : Wh_f;
  float v = (k < 256) ? Wx[(size_t)k * 2048 + n] : Wh[(size_t)(k - 256) * 2048 + n];
  wslice[id] = (__bf16)v;
}

// Persistent bidirectional LSTM. grid = 128 blocks (64/dir) x 512 threads.
// WG owns 8 hidden units; per step: z[64x32] = [x_t | h] @ Wslice via MFMA.
__global__ void __launch_bounds__(512)
lstm_main(const __bf16* __restrict__ xs_g, const __bf16* __restrict__ wslice,
          __bf16* __restrict__ h_g, float* __restrict__ hfin,
          const float* __restrict__ b_f, const float* __restrict__ b_b) {
  __shared__ __align__(16) __bf16 w_lds[32 * 768];   // 48 KiB (weights, staged once)
  __shared__ __align__(16) __bf16 xs_lds[64 * 256];  // 32 KiB (x_t, swizzled rows)
  __shared__ __align__(16) __bf16 hs_lds[64 * 512];  // 64 KiB (h_prev, swizzled rows)
  __shared__ __align__(16) float  z_lds[64 * 36];    // 9 KiB (padded stride 36)

  const int wg   = blockIdx.x;
  const int dir  = wg >> 6;
  const int sl   = wg & 63;
  const int u0   = sl * 8;
  const int tid  = threadIdx.x;
  const int wv   = tid >> 6;
  const int lane = tid & 63;
  const int mt   = wv >> 1;           // M tile (0..3) -> rows mt*16..+16
  const int nt   = wv & 1;            // N tile (0..1) -> cols nt*16..+16
  const int col  = nt * 16 + (lane & 15);
  const int krow = (lane >> 4) * 8;   // k offset of this lane's 8 elems
  const int arow = mt * 16 + (lane & 15);
  const int asw  = arow & 7;          // swizzle key for A reads

  // ---- stage weight slice (once), load B-fragments into registers ----
  {
    const uint4* src = (const uint4*)(wslice + (size_t)wg * (32 * 768));
    uint4* dst = (uint4*)w_lds;
#pragma unroll
    for (int it = 0; it < 6; ++it) dst[it * 512 + tid] = src[it * 512 + tid];
  }
  __syncthreads();
  bf16x8 bfrag[24];
#pragma unroll
  for (int ks = 0; ks < 24; ++ks)
    bfrag[ks] = *(const bf16x8*)(w_lds + col * 768 + ks * 32 + krow);

  // ---- gate-phase constants: thread t -> (row=t>>3, local unit u=t&7) ----
  const int grow = tid >> 3;
  const int gu   = tid & 7;
  const int ug   = u0 + gu;
  const float* bias = dir ? b_b : b_f;
  const float bi  = bias[ug];
  const float bff = bias[512 + ug];
  const float bg  = bias[1024 + ug];
  const float bo  = bias[1536 + ug];
  float c_st = 0.f;
  // swizzled bf16 index of (grow, ug) within one h buffer [64][512]
  const int hswz = grow * 512 + ((((ug >> 3) ^ (grow & 7))) << 3) + (ug & 7);

  // zero-init h buf0 for this dir (each WG covers its 64x8 slice)
  h_g[(size_t)(dir * 2) * 32768 + hswz] = (__bf16)0.f;

  cg::grid_group grid = cg::this_grid();
  grid.sync();

  for (int t = 0; t < T_; ++t) {
    const int teff = dir ? (T_ - 1 - t) : t;
    // ---- stage x_t (32KB) and h_prev (64KB) into LDS (verbatim copies) ----
    {
      const uint4* xsrc = (const uint4*)(xs_g + (size_t)teff * (64 * 256));
      uint4* xdst = (uint4*)xs_lds;
#pragma unroll
      for (int it = 0; it < 4; ++it) xdst[it * 512 + tid] = xsrc[it * 512 + tid];
      const uint4* hsrc = (const uint4*)(h_g + (size_t)(dir * 2 + (t & 1)) * 32768);
      uint4* hdst = (uint4*)hs_lds;
#pragma unroll
      for (int it = 0; it < 8; ++it) hdst[it * 512 + tid] = hsrc[it * 512 + tid];
    }
    __syncthreads();

    // ---- z = [x | h] @ Wslice  (K = 256 + 512) ----
    f32x4 acc = {0.f, 0.f, 0.f, 0.f};
#pragma unroll
    for (int ks = 0; ks < 8; ++ks) {
      const int kx = ks * 32 + krow;
      const int gr = (kx >> 3) ^ asw;
      bf16x8 a = *(const bf16x8*)(xs_lds + arow * 256 + gr * 8);
      acc = __builtin_amdgcn_mfma_f32_16x16x32_bf16(a, bfrag[ks], acc, 0, 0, 0);
    }
#pragma unroll
    for (int ks = 0; ks < 16; ++ks) {
      const int kh = ks * 32 + krow;
      const int gr = (kh >> 3) ^ asw;
      bf16x8 a = *(const bf16x8*)(hs_lds + arow * 512 + gr * 8);
      acc = __builtin_amdgcn_mfma_f32_16x16x32_bf16(a, bfrag[8 + ks], acc, 0, 0, 0);
    }
    // C/D layout: col = lane&15, row = (lane>>4)*4 + i   [m89-verified]
#pragma unroll
    for (int i = 0; i < 4; ++i) {
      const int zr = mt * 16 + (lane >> 4) * 4 + i;
      z_lds[zr * 36 + col] = acc[i];
    }
    __syncthreads();

    // ---- gates (f32): c' = sig(f)c + sig(i)tanh(g); h' = sig(o)tanh(c') ----
    const float zi = z_lds[grow * 36 + gu]      + bi;
    const float zf = z_lds[grow * 36 + 8 + gu]  + bff;
    const float zg = z_lds[grow * 36 + 16 + gu] + bg;
    const float zo = z_lds[grow * 36 + 24 + gu] + bo;
    const float si = 1.f / (1.f + __expf(-zi));
    const float sf = 1.f / (1.f + __expf(-zf));
    const float so = 1.f / (1.f + __expf(-zo));
    const float tg = tanhf(zg);
    c_st = sf * c_st + si * tg;
    const float hv = so * tanhf(c_st);
    h_g[(size_t)(dir * 2 + ((t + 1) & 1)) * 32768 + hswz] = (__bf16)hv;
    if (t == T_ - 1) hfin[(size_t)dir * 32768 + grow * 512 + ug] = hv;
    grid.sync();
  }
}

// Final head: out = sigmoid((hcat @ W1 + b1) @ W2 + b2), all f32. One block.
__global__ void __launch_bounds__(1024)
dense_kernel(const float* __restrict__ hfin, const float* __restrict__ W1,
             const float* __restrict__ b1, const float* __restrict__ W2,
             const float* __restrict__ b2, float* __restrict__ out) {
  __shared__ float hid[64][64];
  const int t = threadIdx.x;
  const int b = t >> 4;
  const int jg = t & 15;           // 4 output cols each
  float a0 = b1[jg * 4 + 0], a1 = b1[jg * 4 + 1], a2 = b1[jg * 4 + 2], a3 = b1[jg * 4 + 3];
#pragma unroll 8
  for (int k = 0; k < 1024; ++k) {
    const float hv = hfin[(size_t)(k >> 9) * 32768 + b * 512 + (k & 511)];
    const float4 w = *(const float4*)(W1 + (size_t)k * 64 + jg * 4);
    a0 += hv * w.x; a1 += hv * w.y; a2 += hv * w.z; a3 += hv * w.w;
  }
  hid[b][jg * 4 + 0] = a0; hid[b][jg * 4 + 1] = a1;
  hid[b][jg * 4 + 2] = a2; hid[b][jg * 4 + 3] = a3;
  __syncthreads();
  if (t < 64) {
    float l = b2[0];
#pragma unroll 8
    for (int j = 0; j < 64; ++j) l += hid[t][j] * W2[j];
    out[t] = 1.f / (1.f + __expf(-l));
  }
}

extern "C" void kernel_launch(void* const* d_in, const int* in_sizes, int n_in,
                              void* d_out, int out_size, void* d_ws, size_t ws_size,
                              hipStream_t stream) {
  const int*   sent = (const int*)d_in[0];
  const float* emb  = (const float*)d_in[1];
  const float* Wx_f = (const float*)d_in[2];
  const float* Wh_f = (const float*)d_in[3];
  const float* b_f  = (const float*)d_in[4];
  const float* Wx_b = (const float*)d_in[5];
  const float* Wh_b = (const float*)d_in[6];
  const float* b_b  = (const float*)d_in[7];
  const float* W1   = (const float*)d_in[8];
  const float* b1   = (const float*)d_in[9];
  const float* W2   = (const float*)d_in[10];
  const float* b2   = (const float*)d_in[11];
  float* out = (float*)d_out;

  char* ws = (char*)d_ws;
  __bf16* xs_g   = (__bf16*)(ws + WS_XS);
  __bf16* wslice = (__bf16*)(ws + WS_WS);
  __bf16* h_g    = (__bf16*)(ws + WS_HG);
  float*  hfin   = (float*)(ws + WS_HF);

  hipLaunchKernelGGL(embed_swz_kernel, dim3(4096), dim3(256), 0, stream, sent, emb, xs_g);
  hipLaunchKernelGGL(wprep_kernel, dim3(12288), dim3(256), 0, stream,
                     Wx_f, Wh_f, Wx_b, Wh_b, wslice);

  void* args[] = {(void*)&xs_g, (void*)&wslice, (void*)&h_g, (void*)&hfin,
                  (void*)&b_f, (void*)&b_b};
  hipLaunchCooperativeKernel((void*)lstm_main, dim3(128), dim3(512), args, 0, stream);

  hipLaunchKernelGGL(dense_kernel, dim3(1), dim3(1024), 0, stream,
                     hfin, W1, b1, W2, b2, out);
}

// Round 2
// 7348.181 us; speedup vs baseline: 1.2926x; 1.2926x over previous
//
#include <hip/hip_runtime.h>
#include <hip/hip_bf16.h>

typedef __bf16 bf16x8 __attribute__((ext_vector_type(8)));
typedef float f32x4 __attribute__((ext_vector_type(4)));

#define B_ 64
#define T_ 512
#define E_ 256
#define U_ 512

// ---------------- workspace layout (bytes) ----------------
// xs_g   : bf16 [T][B][E]  (rows, 16B-granule XOR-swizzled)        16 MiB @ 0
// wslice : bf16 [2][64][32 rows][768 k] rows = unit*4+gate          6 MiB
// h_g    : bf16 [2 dir][2 buf][64][512] (granule-swizzled rows)   256 KiB
// hfin   : f32  [2][64][512] (plain)                              256 KiB
// flags  : u32  [2][64]                                           512 B
static const size_t WS_XS = 0;
static const size_t WS_WS = (size_t)16 << 20;
static const size_t WS_HG = WS_WS + 6291456;
static const size_t WS_HF = WS_HG + 262144;
static const size_t WS_FL = WS_HF + 262144;

// Embedding gather + bf16 convert + granule swizzle.
__global__ void embed_swz_kernel(const int* __restrict__ sent,
                                 const float* __restrict__ emb,
                                 __bf16* __restrict__ xs_g) {
  int id = blockIdx.x * 256 + threadIdx.x;
  int gx = id & 31;          // granule within row (32 x 8 bf16 = 256)
  int b  = (id >> 5) & 63;
  int t  = id >> 11;
  int idx = sent[b * T_ + t];            // sentence is [B][T]
  const float* src = emb + (size_t)idx * E_ + gx * 8;
  bf16x8 v;
#pragma unroll
  for (int j = 0; j < 8; ++j) v[j] = (__bf16)src[j];
  int gs = gx ^ (b & 7);                 // XOR swizzle keyed by batch row
  *(bf16x8*)(xs_g + (size_t)(t * 64 + b) * E_ + gs * 8) = v;
}

// Weight prep: per-WG slices, A-operand layout.
// row c (0..31) = u_local*4 + gate  ->  global col n = gate*512 + sl*8 + u_local
__global__ void wprep_kernel(const float* __restrict__ Wx_f, const float* __restrict__ Wh_f,
                             const float* __restrict__ Wx_b, const float* __restrict__ Wh_b,
                             __bf16* __restrict__ wslice, unsigned* __restrict__ flags) {
  if (blockIdx.x == 0 && threadIdx.x < 128) flags[threadIdx.x] = 0u;  // reset barrier
  int id = blockIdx.x * 256 + threadIdx.x;     // [0, 2*64*32*768)
  int k = id % 768;
  int c = (id / 768) & 31;
  int s = (id / (768 * 32)) & 63;
  int d = id / (768 * 32 * 64);
  int n = (c & 3) * 512 + s * 8 + (c >> 2);
  const float* Wx = d ? Wx_b : Wx_f;
  const float* Wh = d ? Wh_b : Wh_f;
  float v = (k < 256) ? Wx[(size_t)k * 2048 + n] : Wh[(size_t)(k - 256) * 2048 + n];
  wslice[id] = (__bf16)v;
}

// Persistent bidirectional LSTM. 128 WGs (64/dir) x 512 threads.
// Computes z^T: A = weights [32 gate-rows x 768k], B = [x|h]^T [768k x 64 batch].
// D layout (m89): col=lane&15 (batch), row=(lane>>4)*4+i (i = gate) ->
// each thread owns one (unit,batch); gates i,f,g,o are acc[0..3]. Gate math in regs.
__global__ void __launch_bounds__(512)
lstm_main(const __bf16* __restrict__ xs_g, const __bf16* __restrict__ wslice,
          __bf16* __restrict__ h_g, float* __restrict__ hfin,
          const float* __restrict__ b_f, const float* __restrict__ b_b,
          unsigned* __restrict__ flags) {
  __shared__ __align__(16) __bf16 w_lds[32 * 768];    // 48 KiB
  __shared__ __align__(16) __bf16 xh_lds[64 * 768];   // 96 KiB: row b = [x_t | h]
  __shared__ __align__(16) __bf16 h_stage[64 * 8];    // 1 KiB

  const int wg   = blockIdx.x;
  const int dir  = wg >> 6;
  const int sl   = wg & 63;
  const int u0   = sl * 8;
  const int tid  = threadIdx.x;
  const int wv   = tid >> 6;
  const int lane = tid & 63;
  const int mt   = wv >> 2;              // 0..1 : weight-row tile
  const int nt   = wv & 3;               // 0..3 : batch tile
  const int bq   = nt * 16 + (lane & 15);      // this thread's batch
  const int kq   = (lane >> 4) * 8;            // k sub-offset within 32-block
  const int gq   = kq >> 3;                    // granule sub (0..3)
  const int ul   = mt * 4 + (lane >> 4);       // local unit 0..7
  const int ug   = u0 + ul;
  const int wrow = mt * 16 + (lane & 15);
  const int bsw  = bq & 7;
  unsigned* myflags = flags + dir * 64;

  // ---- stage weight slice once; preload A-fragments into registers ----
  {
    const uint4* src = (const uint4*)(wslice + (size_t)wg * (32 * 768));
    uint4* dst = (uint4*)w_lds;
#pragma unroll
    for (int it = 0; it < 6; ++it) dst[it * 512 + tid] = src[it * 512 + tid];
  }
  __syncthreads();
  bf16x8 wfrag[24];
#pragma unroll
  for (int j = 0; j < 24; ++j)
    wfrag[j] = *(const bf16x8*)(w_lds + wrow * 768 + j * 32 + kq);

  const float* bias = dir ? b_b : b_f;
  const float bi  = bias[ug];
  const float bff = bias[512 + ug];
  const float bg  = bias[1024 + ug];
  const float bo  = bias[1536 + ug];
  float c_st = 0.f;

  // ---- prologue: h(0)=0 directly in LDS; stage x_0 ----
  {
    uint4 z4 = {0, 0, 0, 0};
#pragma unroll
    for (int it = 0; it < 8; ++it) {
      int idx = it * 512 + tid;
      *(uint4*)(xh_lds + (idx >> 6) * 768 + 256 + ((idx & 63) << 3)) = z4;
    }
    int teff0 = dir ? (T_ - 1) : 0;
    const uint4* xsrc = (const uint4*)(xs_g + (size_t)teff0 * 16384);
#pragma unroll
    for (int it = 0; it < 4; ++it) {
      int g = it * 512 + tid;
      uint4 v = xsrc[g];
      *(uint4*)(xh_lds + (g >> 5) * 768 + ((g & 31) << 3)) = v;
    }
  }
  __syncthreads();

  for (int t = 0;; ++t) {
    // ---- z^T = W @ [x|h]^T, K = 768, two independent MFMA chains ----
    f32x4 acc0 = {0.f, 0.f, 0.f, 0.f};
    f32x4 acc1 = {0.f, 0.f, 0.f, 0.f};
#pragma unroll
    for (int j = 0; j < 8; ++j) {
      int g = j * 4 + gq;
      bf16x8 a = *(const bf16x8*)(xh_lds + bq * 768 + ((g ^ bsw) << 3));
      if (j & 1) acc1 = __builtin_amdgcn_mfma_f32_16x16x32_bf16(wfrag[j], a, acc1, 0, 0, 0);
      else       acc0 = __builtin_amdgcn_mfma_f32_16x16x32_bf16(wfrag[j], a, acc0, 0, 0, 0);
    }
#pragma unroll
    for (int j = 0; j < 16; ++j) {
      int g = j * 4 + gq;
      bf16x8 a = *(const bf16x8*)(xh_lds + bq * 768 + 256 + ((g ^ bsw) << 3));
      if (j & 1) acc1 = __builtin_amdgcn_mfma_f32_16x16x32_bf16(wfrag[8 + j], a, acc1, 0, 0, 0);
      else       acc0 = __builtin_amdgcn_mfma_f32_16x16x32_bf16(wfrag[8 + j], a, acc0, 0, 0, 0);
    }
    // ---- gates entirely in registers ----
    const float zi = acc0[0] + acc1[0] + bi;
    const float zf = acc0[1] + acc1[1] + bff;
    const float zg = acc0[2] + acc1[2] + bg;
    const float zo = acc0[3] + acc1[3] + bo;
    const float si = 1.f / (1.f + __expf(-zi));
    const float sf = 1.f / (1.f + __expf(-zf));
    const float so = 1.f / (1.f + __expf(-zo));
    const float tg = tanhf(zg);
    c_st = sf * c_st + si * tg;
    const float hv = so * tanhf(c_st);

    if (t == T_ - 1) {
      hfin[(size_t)dir * 32768 + bq * 512 + ug] = hv;
      break;
    }
    h_stage[bq * 8 + ul] = (__bf16)hv;
    __syncthreads();   // S1: MFMA LDS reads done; h_stage complete

    __bf16* hnext = h_g + (size_t)(dir * 2 + ((t + 1) & 1)) * 32768;
    if (wv == 0) {
      // wave 0: publish h-slice, flag, then poll the direction barrier
      uint4 v = *(const uint4*)(h_stage + lane * 8);
      *(uint4*)(hnext + lane * 512 + ((sl ^ (lane & 7)) << 3)) = v;
      __builtin_amdgcn_fence(__ATOMIC_RELEASE, "agent");
      if (tid == 0)
        __hip_atomic_store(myflags + sl, (unsigned)(t + 2), __ATOMIC_RELAXED,
                           __HIP_MEMORY_SCOPE_AGENT);
      const unsigned tgt = (unsigned)(t + 2);
      while (__hip_atomic_load(myflags + lane, __ATOMIC_RELAXED,
                               __HIP_MEMORY_SCOPE_AGENT) < tgt)
        __builtin_amdgcn_s_sleep(1);
    } else {
      // waves 1-7: prefetch x_{t+1} into LDS x-region (MFMA reads done at S1)
      const int teff = dir ? (T_ - 2 - t) : (t + 1);
      const uint4* xsrc = (const uint4*)(xs_g + (size_t)teff * 16384);
      for (int g = tid - 64; g < 2048; g += 448) {
        uint4 v = xsrc[g];
        *(uint4*)(xh_lds + (g >> 5) * 768 + ((g & 31) << 3)) = v;
      }
    }
    __syncthreads();   // S3: barrier passed + x staged
    __builtin_amdgcn_fence(__ATOMIC_ACQUIRE, "agent");  // invalidate L1/L2 for fresh h
    {
      const uint4* hsrc = (const uint4*)hnext;
#pragma unroll
      for (int it = 0; it < 8; ++it) {
        int idx = it * 512 + tid;
        uint4 v = hsrc[idx];
        *(uint4*)(xh_lds + (idx >> 6) * 768 + 256 + ((idx & 63) << 3)) = v;
      }
    }
    __syncthreads();   // S4: xh ready for next step
  }
}

// Final head: out = sigmoid((hcat @ W1 + b1) @ W2 + b2), all f32. One block.
__global__ void __launch_bounds__(1024)
dense_kernel(const float* __restrict__ hfin, const float* __restrict__ W1,
             const float* __restrict__ b1, const float* __restrict__ W2,
             const float* __restrict__ b2, float* __restrict__ out) {
  __shared__ float hid[64][64];
  const int t = threadIdx.x;
  const int b = t >> 4;
  const int jg = t & 15;           // 4 output cols each
  float a0 = b1[jg * 4 + 0], a1 = b1[jg * 4 + 1], a2 = b1[jg * 4 + 2], a3 = b1[jg * 4 + 3];
#pragma unroll 8
  for (int k = 0; k < 1024; ++k) {
    const float hv = hfin[(size_t)(k >> 9) * 32768 + b * 512 + (k & 511)];
    const float4 w = *(const float4*)(W1 + (size_t)k * 64 + jg * 4);
    a0 += hv * w.x; a1 += hv * w.y; a2 += hv * w.z; a3 += hv * w.w;
  }
  hid[b][jg * 4 + 0] = a0; hid[b][jg * 4 + 1] = a1;
  hid[b][jg * 4 + 2] = a2; hid[b][jg * 4 + 3] = a3;
  __syncthreads();
  if (t < 64) {
    float l = b2[0];
#pragma unroll 8
    for (int j = 0; j < 64; ++j) l += hid[t][j] * W2[j];
    out[t] = 1.f / (1.f + __expf(-l));
  }
}

extern "C" void kernel_launch(void* const* d_in, const int* in_sizes, int n_in,
                              void* d_out, int out_size, void* d_ws, size_t ws_size,
                              hipStream_t stream) {
  const int*   sent = (const int*)d_in[0];
  const float* emb  = (const float*)d_in[1];
  const float* Wx_f = (const float*)d_in[2];
  const float* Wh_f = (const float*)d_in[3];
  const float* b_f  = (const float*)d_in[4];
  const float* Wx_b = (const float*)d_in[5];
  const float* Wh_b = (const float*)d_in[6];
  const float* b_b  = (const float*)d_in[7];
  const float* W1   = (const float*)d_in[8];
  const float* b1   = (const float*)d_in[9];
  const float* W2   = (const float*)d_in[10];
  const float* b2   = (const float*)d_in[11];
  float* out = (float*)d_out;

  char* ws = (char*)d_ws;
  __bf16*   xs_g   = (__bf16*)(ws + WS_XS);
  __bf16*   wslice = (__bf16*)(ws + WS_WS);
  __bf16*   h_g    = (__bf16*)(ws + WS_HG);
  float*    hfin   = (float*)(ws + WS_HF);
  unsigned* flags  = (unsigned*)(ws + WS_FL);

  hipLaunchKernelGGL(embed_swz_kernel, dim3(4096), dim3(256), 0, stream, sent, emb, xs_g);
  hipLaunchKernelGGL(wprep_kernel, dim3(12288), dim3(256), 0, stream,
                     Wx_f, Wh_f, Wx_b, Wh_b, wslice, flags);

  void* args[] = {(void*)&xs_g, (void*)&wslice, (void*)&h_g, (void*)&hfin,
                  (void*)&b_f, (void*)&b_b, (void*)&flags};
  hipLaunchCooperativeKernel((void*)lstm_main, dim3(128), dim3(512), args, 0, stream);

  hipLaunchKernelGGL(dense_kernel, dim3(1), dim3(1024), 0, stream,
                     hfin, W1, b1, W2, b2, out);
}

// Round 3
// 2239.118 us; speedup vs baseline: 4.2421x; 3.2817x over previous
//
#include <hip/hip_runtime.h>
#include <hip/hip_bf16.h>

typedef __bf16 bf16x8 __attribute__((ext_vector_type(8)));
typedef float f32x4 __attribute__((ext_vector_type(4)));
typedef unsigned int u32;
typedef unsigned long long u64;

#define B_ 64
#define T_ 512
#define E_ 256
#define U_ 512

// ---------------- workspace layout (bytes) ----------------
// xs_g   : bf16 [T][B][E]  (rows, 16B-granule XOR-swizzled)        16 MiB @ 0
// wslice : bf16 [2][64][32 rows][768 k] rows c = ul*4+gate          6 MiB
// h_g    : bf16 [2 dir][2 buf][64][512] (granule-swizzled rows)   256 KiB
// hfin   : f32  [2][64][512] (plain)                              256 KiB
// flags  : u32  [2][64]
static const size_t WS_XS = 0;
static const size_t WS_WS = (size_t)16 << 20;
static const size_t WS_HG = WS_WS + 6291456;
static const size_t WS_HF = WS_HG + 262144;
static const size_t WS_FL = WS_HF + 262144;

__device__ __forceinline__ float fsigm(float x) { return 1.f / (1.f + __expf(-x)); }
__device__ __forceinline__ float ftanh(float x) {
  float e = __expf(2.f * fabsf(x));
  float r = 1.f - 2.f / (e + 1.f);
  return copysignf(r, x);
}

// Embedding gather + bf16 convert + granule swizzle.
__global__ void embed_swz_kernel(const int* __restrict__ sent,
                                 const float* __restrict__ emb,
                                 __bf16* __restrict__ xs_g) {
  int id = blockIdx.x * 256 + threadIdx.x;
  int gx = id & 31;          // granule within row (32 x 8 bf16 = 256)
  int b  = (id >> 5) & 63;
  int t  = id >> 11;
  int idx = sent[b * T_ + t];            // sentence is [B][T]
  const float* src = emb + (size_t)idx * E_ + gx * 8;
  bf16x8 v;
#pragma unroll
  for (int j = 0; j < 8; ++j) v[j] = (__bf16)src[j];
  int gs = gx ^ (b & 7);                 // XOR swizzle keyed by batch row
  *(bf16x8*)(xs_g + (size_t)(t * 64 + b) * E_ + gs * 8) = v;
}

// Weight prep via LDS transpose: block = (dir, s-slice). Coalesced in, coalesced out.
// out row c (0..31) = ul*4 + gate  ->  global col n = gate*512 + s*8 + ul
__global__ void __launch_bounds__(256)
wprep_kernel(const float* __restrict__ Wx_f, const float* __restrict__ Wh_f,
             const float* __restrict__ Wx_b, const float* __restrict__ Wh_b,
             __bf16* __restrict__ wslice, unsigned* __restrict__ flags) {
  __shared__ __bf16 tile[32 * 770];   // stride 770: conflict-free
  const int bid = blockIdx.x;
  const int d = bid >> 6;
  const int s = bid & 63;
  const int tid = threadIdx.x;
  if (bid == 0 && tid < 128) flags[tid] = 0u;   // reset the direction barriers
  const float* Wx = d ? Wx_b : Wx_f;
  const float* Wh = d ? Wh_b : Wh_f;
#pragma unroll
  for (int it = 0; it < 96; ++it) {
    int id2 = it * 256 + tid;          // [0, 768*32)
    int k = id2 >> 5;
    int c = id2 & 31;
    int n = (c & 3) * 512 + s * 8 + (c >> 2);
    float v = (k < 256) ? Wx[(size_t)k * 2048 + n] : Wh[(size_t)(k - 256) * 2048 + n];
    tile[c * 770 + k] = (__bf16)v;
  }
  __syncthreads();
  u32* outp = (u32*)(wslice + ((size_t)(d * 64 + s) * 32) * 768);
#pragma unroll
  for (int it = 0; it < 48; ++it) {
    int idx = it * 256 + tid;          // [0, 32*384)
    int c = idx / 384;
    int w = idx - c * 384;
    outp[c * 384 + w] = *(const u32*)(tile + c * 770 + w * 2);
  }
}

// Persistent bidirectional LSTM. 128 WGs (64/dir) x 512 threads.
// z^T = W @ [x|h]^T; D layout (m89): col=lane&15 (batch), row=(lane>>4)*4+i ->
// thread owns one (unit,batch); acc[0..3] = gates i,f,g,o. Gate math in regs.
// Cross-WG h exchange: per-access agent-scope atomics (no cache-wide fences).
__global__ void __launch_bounds__(512)
lstm_main(const __bf16* __restrict__ xs_g, const __bf16* __restrict__ wslice,
          __bf16* __restrict__ h_g, float* __restrict__ hfin,
          const float* __restrict__ b_f, const float* __restrict__ b_b,
          unsigned* __restrict__ flags) {
  __shared__ __align__(16) __bf16 xbuf[2][64 * 256];  // 2 x 32 KiB, double-buffered x_t
  __shared__ __align__(16) __bf16 hbuf[64 * 512];     // 64 KiB h (init: weight staging tmp)
  __shared__ __align__(16) __bf16 h_stage[64 * 8];    // 1 KiB

  const int wg   = blockIdx.x;
  const int dir  = wg >> 6;
  const int sl   = wg & 63;
  const int tid  = threadIdx.x;
  const int wv   = tid >> 6;
  const int lane = tid & 63;
  const int mt   = wv >> 2;              // 0..1 : weight-row tile
  const int nt   = wv & 3;               // 0..3 : batch tile
  const int bq   = nt * 16 + (lane & 15);      // this thread's batch
  const int kq   = (lane >> 4) * 8;            // k sub-offset within 32-block
  const int gq   = kq >> 3;                    // granule sub (0..3)
  const int ul   = mt * 4 + (lane >> 4);       // local unit 0..7
  const int ug   = sl * 8 + ul;
  const int wrow = mt * 16 + (lane & 15);
  const int bsw  = bq & 7;
  unsigned* myflags = flags + dir * 64;

  // ---- stage weight slice once (into hbuf as tmp); preload A-frags to regs ----
  {
    const uint4* src = (const uint4*)(wslice + (size_t)wg * (32 * 768));
    uint4* dst = (uint4*)hbuf;
#pragma unroll
    for (int it = 0; it < 6; ++it) dst[it * 512 + tid] = src[it * 512 + tid];
  }
  __syncthreads();
  bf16x8 wfrag[24];
#pragma unroll
  for (int j = 0; j < 24; ++j)
    wfrag[j] = *(const bf16x8*)(hbuf + wrow * 768 + j * 32 + kq);

  const float* bias = dir ? b_b : b_f;
  const float bi  = bias[ug];
  const float bff = bias[512 + ug];
  const float bg  = bias[1024 + ug];
  const float bo  = bias[1536 + ug];
  float c_st = 0.f;

  // ---- stage x_0 ----
  {
    int teff0 = dir ? (T_ - 1) : 0;
    const uint4* xsrc = (const uint4*)(xs_g + (size_t)teff0 * 16384);
    uint4* xdst = (uint4*)xbuf[0];
#pragma unroll
    for (int it = 0; it < 4; ++it) xdst[it * 512 + tid] = xsrc[it * 512 + tid];
  }
  __syncthreads();   // also covers wfrag preload reads of hbuf

  __bf16* hg0 = h_g + (size_t)dir * 2 * 32768;

  for (int t = 0;; ++t) {
    // ---- [A] x-part MFMAs (independent of h -> overlaps peers' h publish) ----
    f32x4 acc0 = {0.f, 0.f, 0.f, 0.f};
    f32x4 acc1 = {0.f, 0.f, 0.f, 0.f};
    const __bf16* xb = xbuf[t & 1];
#pragma unroll
    for (int j = 0; j < 8; ++j) {
      int g = j * 4 + gq;
      bf16x8 a = *(const bf16x8*)(xb + bq * 256 + ((g ^ bsw) << 3));
      if (j & 1) acc1 = __builtin_amdgcn_mfma_f32_16x16x32_bf16(wfrag[j], a, acc1, 0, 0, 0);
      else       acc0 = __builtin_amdgcn_mfma_f32_16x16x32_bf16(wfrag[j], a, acc0, 0, 0, 0);
    }

    if (t > 0) {
      // ---- [B] poll direction barrier: h(t) published by all 64 WGs ----
      const unsigned tgt = (unsigned)t;
      while (__hip_atomic_load(myflags + lane, __ATOMIC_RELAXED,
                               __HIP_MEMORY_SCOPE_AGENT) < tgt)
        __builtin_amdgcn_s_sleep(1);
      // ---- [C] stage h(t): verbatim 64KB copy via coherent u64 loads ----
      u64* hsrc = (u64*)(hg0 + (size_t)(t & 1) * 32768);
      u64* hdst = (u64*)hbuf;
      u64 v[16];
#pragma unroll
      for (int it = 0; it < 16; ++it)
        v[it] = __hip_atomic_load(hsrc + it * 512 + tid, __ATOMIC_RELAXED,
                                  __HIP_MEMORY_SCOPE_AGENT);
#pragma unroll
      for (int it = 0; it < 16; ++it)
        hdst[it * 512 + tid] = v[it];
      __syncthreads();
      // ---- [D] h-part MFMAs ----
#pragma unroll
      for (int j = 0; j < 16; ++j) {
        int g = j * 4 + gq;
        bf16x8 a = *(const bf16x8*)(hbuf + bq * 512 + ((g ^ bsw) << 3));
        if (j & 1) acc1 = __builtin_amdgcn_mfma_f32_16x16x32_bf16(wfrag[8 + j], a, acc1, 0, 0, 0);
        else       acc0 = __builtin_amdgcn_mfma_f32_16x16x32_bf16(wfrag[8 + j], a, acc0, 0, 0, 0);
      }
    }

    // ---- gates in registers ----
    const float zi = acc0[0] + acc1[0] + bi;
    const float zf = acc0[1] + acc1[1] + bff;
    const float zg = acc0[2] + acc1[2] + bg;
    const float zo = acc0[3] + acc1[3] + bo;
    c_st = fsigm(zf) * c_st + fsigm(zi) * ftanh(zg);
    const float hv = fsigm(zo) * ftanh(c_st);

    if (t == T_ - 1) {
      hfin[(size_t)dir * 32768 + bq * 512 + ug] = hv;
      break;
    }
    h_stage[bq * 8 + ul] = (__bf16)hv;
    __syncthreads();   // h_stage complete; hbuf MFMA reads done

    if (wv == 0) {
      // ---- [E] wave 0: publish 1KB slice via coherent u64 stores, then flag ----
      union { uint4 q; u64 w[2]; } uu;
      uu.q = *(const uint4*)(h_stage + lane * 8);
      u64* hq = (u64*)(hg0 + (size_t)((t + 1) & 1) * 32768) + lane * 128 +
                ((sl ^ (lane & 7)) << 1);
      __hip_atomic_store(hq + 0, uu.w[0], __ATOMIC_RELAXED, __HIP_MEMORY_SCOPE_AGENT);
      __hip_atomic_store(hq + 1, uu.w[1], __ATOMIC_RELAXED, __HIP_MEMORY_SCOPE_AGENT);
      asm volatile("s_waitcnt vmcnt(0)" ::: "memory");
      if (tid == 0)
        __hip_atomic_store(myflags + sl, (unsigned)(t + 1), __ATOMIC_RELAXED,
                           __HIP_MEMORY_SCOPE_AGENT);
    } else {
      // waves 1-7: prefetch x_{t+1} (plain cached loads; L2 stays warm now)
      const int teff = dir ? (T_ - 2 - t) : (t + 1);
      const uint4* xsrc = (const uint4*)(xs_g + (size_t)teff * 16384);
      uint4* xdst = (uint4*)xbuf[(t + 1) & 1];
      for (int g = tid - 64; g < 2048; g += 448) xdst[g] = xsrc[g];
    }
    __syncthreads();
  }
}

// Final head: out = sigmoid((hcat @ W1 + b1) @ W2 + b2), all f32. One block.
__global__ void __launch_bounds__(1024)
dense_kernel(const float* __restrict__ hfin, const float* __restrict__ W1,
             const float* __restrict__ b1, const float* __restrict__ W2,
             const float* __restrict__ b2, float* __restrict__ out) {
  __shared__ float hid[64][64];
  const int t = threadIdx.x;
  const int b = t >> 4;
  const int jg = t & 15;           // 4 output cols each
  float a0 = b1[jg * 4 + 0], a1 = b1[jg * 4 + 1], a2 = b1[jg * 4 + 2], a3 = b1[jg * 4 + 3];
#pragma unroll 8
  for (int k = 0; k < 1024; ++k) {
    const float hv = hfin[(size_t)(k >> 9) * 32768 + b * 512 + (k & 511)];
    const float4 w = *(const float4*)(W1 + (size_t)k * 64 + jg * 4);
    a0 += hv * w.x; a1 += hv * w.y; a2 += hv * w.z; a3 += hv * w.w;
  }
  hid[b][jg * 4 + 0] = a0; hid[b][jg * 4 + 1] = a1;
  hid[b][jg * 4 + 2] = a2; hid[b][jg * 4 + 3] = a3;
  __syncthreads();
  if (t < 64) {
    float l = b2[0];
#pragma unroll 8
    for (int j = 0; j < 64; ++j) l += hid[t][j] * W2[j];
    out[t] = 1.f / (1.f + __expf(-l));
  }
}

extern "C" void kernel_launch(void* const* d_in, const int* in_sizes, int n_in,
                              void* d_out, int out_size, void* d_ws, size_t ws_size,
                              hipStream_t stream) {
  const int*   sent = (const int*)d_in[0];
  const float* emb  = (const float*)d_in[1];
  const float* Wx_f = (const float*)d_in[2];
  const float* Wh_f = (const float*)d_in[3];
  const float* b_f  = (const float*)d_in[4];
  const float* Wx_b = (const float*)d_in[5];
  const float* Wh_b = (const float*)d_in[6];
  const float* b_b  = (const float*)d_in[7];
  const float* W1   = (const float*)d_in[8];
  const float* b1   = (const float*)d_in[9];
  const float* W2   = (const float*)d_in[10];
  const float* b2   = (const float*)d_in[11];
  float* out = (float*)d_out;

  char* ws = (char*)d_ws;
  __bf16*   xs_g   = (__bf16*)(ws + WS_XS);
  __bf16*   wslice = (__bf16*)(ws + WS_WS);
  __bf16*   h_g    = (__bf16*)(ws + WS_HG);
  float*    hfin   = (float*)(ws + WS_HF);
  unsigned* flags  = (unsigned*)(ws + WS_FL);

  hipLaunchKernelGGL(embed_swz_kernel, dim3(4096), dim3(256), 0, stream, sent, emb, xs_g);
  hipLaunchKernelGGL(wprep_kernel, dim3(128), dim3(256), 0, stream,
                     Wx_f, Wh_f, Wx_b, Wh_b, wslice, flags);

  void* args[] = {(void*)&xs_g, (void*)&wslice, (void*)&h_g, (void*)&hfin,
                  (void*)&b_f, (void*)&b_b, (void*)&flags};
  hipLaunchCooperativeKernel((void*)lstm_main, dim3(128), dim3(512), args, 0, stream);

  hipLaunchKernelGGL(dense_kernel, dim3(1), dim3(1024), 0, stream,
                     hfin, W1, b1, W2, b2, out);
}

// Round 4
// 1575.538 us; speedup vs baseline: 6.0288x; 1.4212x over previous
//
#include <hip/hip_runtime.h>
#include <hip/hip_bf16.h>

typedef __bf16 bf16x8 __attribute__((ext_vector_type(8)));
typedef float f32x4 __attribute__((ext_vector_type(4)));
typedef unsigned int u32;
typedef unsigned long long u64;

#define T_ 512
#define E_ 256
#define U_ 512

// ---------------- workspace layout (bytes) ----------------
// xs_g : bf16 [T][64][256] (granule-swizzled rows)                 16 MiB
// w2   : bf16 [2 dir][16 us][8 wv][24 j][64 lane][8] frag-ordered   6 MiB
// h_g  : bf16 [2 dir][2 buf][64 b][512 u] (granule-swizzled rows) 256 KiB
// hfin : f32  [2][64][512] (plain)                                256 KiB
// flags: u32  [2 dir][64]  (index q*16+us)
static const size_t WS_XS = 0;
static const size_t WS_W2 = (size_t)16 << 20;
static const size_t WS_HG = WS_W2 + 6291456;
static const size_t WS_HF = WS_HG + 262144;
static const size_t WS_FL = WS_HF + 262144;

__device__ __forceinline__ float fsigm(float x) { return 1.f / (1.f + __expf(-x)); }
__device__ __forceinline__ float ftanh(float x) {
  float e = __expf(2.f * fabsf(x));
  float r = 1.f - 2.f / (e + 1.f);
  return copysignf(r, x);
}

// Embedding gather + bf16 convert + granule swizzle.
__global__ void embed_swz_kernel(const int* __restrict__ sent,
                                 const float* __restrict__ emb,
                                 __bf16* __restrict__ xs_g) {
  int id = blockIdx.x * 256 + threadIdx.x;
  int gx = id & 31;          // granule within row (32 x 8 bf16 = 256)
  int b  = (id >> 5) & 63;
  int t  = id >> 11;
  int idx = sent[b * T_ + t];            // sentence is [B][T]
  const float* src = emb + (size_t)idx * E_ + gx * 8;
  bf16x8 v;
#pragma unroll
  for (int j = 0; j < 8; ++j) v[j] = (__bf16)src[j];
  int gs = gx ^ (b & 7);                 // XOR swizzle keyed by batch row
  *(bf16x8*)(xs_g + (size_t)(t * 64 + b) * E_ + gs * 8) = v;
}

// Weight prep: fragment-ordered layout so lstm_main loads wfrag with fully
// coalesced 16B/lane global reads.
// granule og = (((d*16+us)*8+wv)*24 + j)*64 + lane holds W row c = wv*16+(lane&15)
// (c = ul*4+gate, global col n = gate*512 + us*32 + ul), k = j*32+(lane>>4)*8 .. +8.
__global__ void __launch_bounds__(256)
wprep_kernel(const float* __restrict__ Wx_f, const float* __restrict__ Wh_f,
             const float* __restrict__ Wx_b, const float* __restrict__ Wh_b,
             __bf16* __restrict__ w2, u32* __restrict__ flags) {
  int bid = blockIdx.x;              // ((d*16+us)*8+wv)*6 + jg
  int tid = threadIdx.x;
  if (bid == 0 && tid < 128) flags[tid] = 0u;   // reset direction barriers
  int jg = bid % 6;
  int wv = (bid / 6) & 7;
  int us = (bid / 48) & 15;
  int d  = bid / 768;
  int j    = jg * 4 + (tid >> 6);
  int lane = tid & 63;
  int c    = wv * 16 + (lane & 15);   // slice row 0..127
  int ul   = c >> 2, gate = c & 3;
  int n    = gate * 512 + us * 32 + ul;
  int k0   = j * 32 + (lane >> 4) * 8;
  const float* Wx = d ? Wx_b : Wx_f;
  const float* Wh = d ? Wh_b : Wh_f;
  bf16x8 v;
#pragma unroll
  for (int e = 0; e < 8; ++e) {
    int k = k0 + e;
    float f = (k < 256) ? Wx[(size_t)k * 2048 + n] : Wh[(size_t)(k - 256) * 2048 + n];
    v[e] = (__bf16)f;
  }
  size_t og = ((size_t)((d * 16 + us) * 8 + wv) * 24 + j) * 64 + lane;
  *(bf16x8*)(w2 + og * 8) = v;
}

// Persistent bidirectional LSTM. 128 WGs x 512 thr.
// WG = (dir, us 0..15, q 0..3): units 32us..32us+31, batches 16q..16q+15.
// z^T = W @ [x|h]^T ; D (m89): col=lane&15 (batch), row=(lane>>4)*4+i (gate i) ->
// thread owns (unit ul=wv*4+kq, batch), acc[0..3]=i,f,g,o. Gates in registers.
// Cross-WG h: quarter-scoped flags, per-wave poll of its 2 producers.
__global__ void __launch_bounds__(512)
lstm_main(const __bf16* __restrict__ xs_g, const __bf16* __restrict__ w2,
          __bf16* __restrict__ h_g, float* __restrict__ hfin,
          const float* __restrict__ b_f, const float* __restrict__ b_b,
          u32* __restrict__ flags) {
  __shared__ __align__(16) __bf16 xbuf[2][16 * 256];   // 2 x 8 KiB
  __shared__ __align__(16) __bf16 hbuf[16 * 512];      // 16 KiB
  __shared__ __align__(16) __bf16 h_stage[16 * 40];    // padded stride 40 units

  const int wg   = blockIdx.x;
  const int dir  = wg >> 6;
  const int sl   = wg & 63;
  const int us   = sl >> 2;
  const int q    = sl & 3;
  const int tid  = threadIdx.x;
  const int wv   = tid >> 6;
  const int lane = tid & 63;
  const int bq_l = lane & 15;          // local batch / D col
  const int kq   = lane >> 4;          // k-quarter
  const int bsw  = bq_l & 7;           // swizzle key
  const int ul_own = wv * 4 + kq;      // owned local unit (0..31)
  const int u_own  = us * 32 + ul_own;
  const int b_own  = q * 16 + bq_l;
  u32* myflags = flags + dir * 64 + q * 16;

  // ---- weight fragments: direct coalesced global->reg ----
  bf16x8 wfrag[24];
  {
    const bf16x8* wp = (const bf16x8*)w2 +
                       ((size_t)((dir * 16 + us) * 8 + wv) * 24) * 64 + lane;
#pragma unroll
    for (int j = 0; j < 24; ++j) wfrag[j] = wp[j * 64];
  }

  const float* bias = dir ? b_b : b_f;
  const float bi  = bias[u_own];
  const float bff = bias[512 + u_own];
  const float bg  = bias[1024 + u_own];
  const float bo  = bias[1536 + u_own];
  float c_st = 0.f;

  // ---- stage x_0 (8 KiB: 512 granules, 1 per thread) ----
  {
    int t0 = dir ? (T_ - 1) : 0;
    const uint4* xsrc = (const uint4*)(xs_g + ((size_t)t0 * 64 + q * 16) * 256);
    ((uint4*)xbuf[0])[tid] = xsrc[tid];
  }
  __syncthreads();

  __bf16* hg0 = h_g + (size_t)dir * 2 * 32768;
  // h-load assignment: wave wv copies producers {2wv, 2wv+1}
  const int pidx = 2 * wv + (lane >> 5);
  const int sub  = lane & 31;
  const int pb   = sub >> 1;                 // batch row 0..15
  const int pg0  = (sub & 1) * 2;            // granule pair base
  const int pg_a = (4 * pidx + pg0)     ^ (pb & 7);
  const int pg_b = (4 * pidx + pg0 + 1) ^ (pb & 7);

  for (int t = 0;; ++t) {
    // ---- [A] x-part MFMAs (independent of h; overlaps peers' publish) ----
    f32x4 acc0 = {0.f, 0.f, 0.f, 0.f};
    f32x4 acc1 = {0.f, 0.f, 0.f, 0.f};
    const __bf16* xb = xbuf[t & 1];
#pragma unroll
    for (int j = 0; j < 8; ++j) {
      int g = j * 4 + kq;
      bf16x8 a = *(const bf16x8*)(xb + bq_l * 256 + ((g ^ bsw) << 3));
      if (j & 1) acc1 = __builtin_amdgcn_mfma_f32_16x16x32_bf16(wfrag[j], a, acc1, 0, 0, 0);
      else       acc0 = __builtin_amdgcn_mfma_f32_16x16x32_bf16(wfrag[j], a, acc0, 0, 0, 0);
    }

    if (t > 0) {
      // ---- [B] per-wave poll of this wave's 2 producers ----
      const unsigned tgt = (unsigned)t;
      while (__hip_atomic_load(myflags + pidx, __ATOMIC_RELAXED,
                               __HIP_MEMORY_SCOPE_AGENT) < tgt)
        __builtin_amdgcn_s_sleep(1);
      // ---- [C] copy 2 KiB per producer pair (coherent u64 loads) ----
      const u64* hsrc = (const u64*)(hg0 + (size_t)(t & 1) * 32768);
      const int rbase = (q * 16 + pb) * 128;
      u64 va0 = __hip_atomic_load(hsrc + rbase + pg_a * 2,     __ATOMIC_RELAXED, __HIP_MEMORY_SCOPE_AGENT);
      u64 va1 = __hip_atomic_load(hsrc + rbase + pg_a * 2 + 1, __ATOMIC_RELAXED, __HIP_MEMORY_SCOPE_AGENT);
      u64 vb0 = __hip_atomic_load(hsrc + rbase + pg_b * 2,     __ATOMIC_RELAXED, __HIP_MEMORY_SCOPE_AGENT);
      u64 vb1 = __hip_atomic_load(hsrc + rbase + pg_b * 2 + 1, __ATOMIC_RELAXED, __HIP_MEMORY_SCOPE_AGENT);
      u64* hd = (u64*)hbuf;
      const int lbase = pb * 128;
      hd[lbase + pg_a * 2]     = va0;
      hd[lbase + pg_a * 2 + 1] = va1;
      hd[lbase + pg_b * 2]     = vb0;
      hd[lbase + pg_b * 2 + 1] = vb1;
      __syncthreads();
      // ---- [D] h-part MFMAs ----
#pragma unroll
      for (int j = 0; j < 16; ++j) {
        int g = j * 4 + kq;
        bf16x8 a = *(const bf16x8*)(hbuf + bq_l * 512 + ((g ^ bsw) << 3));
        if (j & 1) acc1 = __builtin_amdgcn_mfma_f32_16x16x32_bf16(wfrag[8 + j], a, acc1, 0, 0, 0);
        else       acc0 = __builtin_amdgcn_mfma_f32_16x16x32_bf16(wfrag[8 + j], a, acc0, 0, 0, 0);
      }
    }

    // ---- gates in registers ----
    const float zi = acc0[0] + acc1[0] + bi;
    const float zf = acc0[1] + acc1[1] + bff;
    const float zg = acc0[2] + acc1[2] + bg;
    const float zo = acc0[3] + acc1[3] + bo;
    c_st = fsigm(zf) * c_st + fsigm(zi) * ftanh(zg);
    const float hv = fsigm(zo) * ftanh(c_st);

    if (t == T_ - 1) {
      hfin[(size_t)dir * 32768 + b_own * 512 + u_own] = hv;
      break;
    }
    h_stage[bq_l * 40 + ul_own] = (__bf16)hv;
    __syncthreads();   // h_stage complete; hbuf/xbuf reads done

    if (wv == 0) {
      // ---- [E] publish 1 KiB (lane = b*4+gi -> granule 4us+gi of batch b) ----
      const int b  = lane >> 2;
      const int gi = lane & 3;
      union { uint4 qv; u64 w[2]; } uu;
      uu.qv = *(const uint4*)(h_stage + b * 40 + gi * 8);
      const int gp = (4 * us + gi) ^ (b & 7);
      u64* hq = (u64*)(hg0 + (size_t)((t + 1) & 1) * 32768) + (q * 16 + b) * 128 + gp * 2;
      __hip_atomic_store(hq,     uu.w[0], __ATOMIC_RELAXED, __HIP_MEMORY_SCOPE_AGENT);
      __hip_atomic_store(hq + 1, uu.w[1], __ATOMIC_RELAXED, __HIP_MEMORY_SCOPE_AGENT);
      asm volatile("s_waitcnt vmcnt(0)" ::: "memory");
      if (lane == 0)
        __hip_atomic_store(myflags + us, (unsigned)(t + 1), __ATOMIC_RELAXED,
                           __HIP_MEMORY_SCOPE_AGENT);
    } else {
      // waves 1-7: prefetch x_{t+1} (8 KiB)
      const int teff = dir ? (T_ - 2 - t) : (t + 1);
      const uint4* xsrc = (const uint4*)(xs_g + ((size_t)teff * 64 + q * 16) * 256);
      uint4* xdst = (uint4*)xbuf[(t + 1) & 1];
      for (int g2 = tid - 64; g2 < 512; g2 += 448) xdst[g2] = xsrc[g2];
    }
    __syncthreads();
  }
}

// Final head: out = sigmoid((hcat @ W1 + b1) @ W2 + b2), all f32. One block.
__global__ void __launch_bounds__(1024)
dense_kernel(const float* __restrict__ hfin, const float* __restrict__ W1,
             const float* __restrict__ b1, const float* __restrict__ W2,
             const float* __restrict__ b2, float* __restrict__ out) {
  __shared__ float hid[64][64];
  const int t = threadIdx.x;
  const int b = t >> 4;
  const int jg = t & 15;           // 4 output cols each
  float a0 = b1[jg * 4 + 0], a1 = b1[jg * 4 + 1], a2 = b1[jg * 4 + 2], a3 = b1[jg * 4 + 3];
#pragma unroll 8
  for (int k = 0; k < 1024; ++k) {
    const float hv = hfin[(size_t)(k >> 9) * 32768 + b * 512 + (k & 511)];
    const float4 w = *(const float4*)(W1 + (size_t)k * 64 + jg * 4);
    a0 += hv * w.x; a1 += hv * w.y; a2 += hv * w.z; a3 += hv * w.w;
  }
  hid[b][jg * 4 + 0] = a0; hid[b][jg * 4 + 1] = a1;
  hid[b][jg * 4 + 2] = a2; hid[b][jg * 4 + 3] = a3;
  __syncthreads();
  if (t < 64) {
    float l = b2[0];
#pragma unroll 8
    for (int j = 0; j < 64; ++j) l += hid[t][j] * W2[j];
    out[t] = 1.f / (1.f + __expf(-l));
  }
}

extern "C" void kernel_launch(void* const* d_in, const int* in_sizes, int n_in,
                              void* d_out, int out_size, void* d_ws, size_t ws_size,
                              hipStream_t stream) {
  const int*   sent = (const int*)d_in[0];
  const float* emb  = (const float*)d_in[1];
  const float* Wx_f = (const float*)d_in[2];
  const float* Wh_f = (const float*)d_in[3];
  const float* b_f  = (const float*)d_in[4];
  const float* Wx_b = (const float*)d_in[5];
  const float* Wh_b = (const float*)d_in[6];
  const float* b_b  = (const float*)d_in[7];
  const float* W1   = (const float*)d_in[8];
  const float* b1   = (const float*)d_in[9];
  const float* W2   = (const float*)d_in[10];
  const float* b2   = (const float*)d_in[11];
  float* out = (float*)d_out;

  char* ws = (char*)d_ws;
  __bf16* xs_g = (__bf16*)(ws + WS_XS);
  __bf16* w2   = (__bf16*)(ws + WS_W2);
  __bf16* h_g  = (__bf16*)(ws + WS_HG);
  float*  hfin = (float*)(ws + WS_HF);
  u32*    flags = (u32*)(ws + WS_FL);

  hipLaunchKernelGGL(embed_swz_kernel, dim3(4096), dim3(256), 0, stream, sent, emb, xs_g);
  hipLaunchKernelGGL(wprep_kernel, dim3(1536), dim3(256), 0, stream,
                     Wx_f, Wh_f, Wx_b, Wh_b, w2, flags);

  void* args[] = {(void*)&xs_g, (void*)&w2, (void*)&h_g, (void*)&hfin,
                  (void*)&b_f, (void*)&b_b, (void*)&flags};
  hipLaunchCooperativeKernel((void*)lstm_main, dim3(128), dim3(512), args, 0, stream);

  hipLaunchKernelGGL(dense_kernel, dim3(1), dim3(1024), 0, stream,
                     hfin, W1, b1, W2, b2, out);
}